// Round 6
// baseline (525.634 us; speedup 1.0000x reference)
//
#include <hip/hip_runtime.h>

#define POOL_SHIFT 2
#define GRID_DIM 64
#define NUM_CELLS 4096
#define NCH 64
#define BATCH 64
#define NSEG (BATCH * NUM_CELLS)   // 262,144 cells
#define SCAN_BLOCKS 1024           // NSEG / 256
#define RANK_BITS 14
#define RANK_MASK ((1u << RANK_BITS) - 1u)
#define GATHER_REPS 3              // MEASUREMENT ROUND: 3x idempotent gather

typedef float vf4 __attribute__((ext_vector_type(4)));

// ---- K1: histogram + packed (cell,rank) per point ----
__global__ __launch_bounds__(256) void count_kernel(
    const int* __restrict__ pos, const int* __restrict__ batch,
    unsigned int* __restrict__ counts, unsigned int* __restrict__ cellrank, int n) {
    int stride = gridDim.x * blockDim.x;
    for (int p = blockIdx.x * blockDim.x + threadIdx.x; p < n; p += stride) {
        long long t = __builtin_nontemporal_load((const long long*)pos + p);
        int px = (int)t;               // pos[p][0]
        int py = (int)(t >> 32);       // pos[p][1]
        int b  = __builtin_nontemporal_load(&batch[p]);
        int c  = b * NUM_CELLS + (px >> POOL_SHIFT) * GRID_DIM + (py >> POOL_SHIFT);
        unsigned int r = atomicAdd(&counts[c], 1u);
        __builtin_nontemporal_store(((unsigned int)c << RANK_BITS) | r, &cellrank[p]);
    }
}

// ---- K2a: per-256-chunk sums (wave shuffle reduce, 1 barrier) ----
__global__ __launch_bounds__(256) void reduce_kernel(
    const unsigned int* __restrict__ counts, unsigned int* __restrict__ blocksum) {
    __shared__ unsigned int ws[4];
    int t = threadIdx.x;
    unsigned int v = counts[blockIdx.x * 256 + t];
    #pragma unroll
    for (int off = 1; off < 64; off <<= 1) v += __shfl_xor((int)v, off, 64);
    if ((t & 63) == 0) ws[t >> 6] = v;
    __syncthreads();
    if (t == 0) blocksum[blockIdx.x] = ws[0] + ws[1] + ws[2] + ws[3];
}

// ---- K2b: exclusive scan of the 1024 chunk sums (single block, shfl scan) ----
__global__ __launch_bounds__(1024) void scanblock_kernel(
    const unsigned int* __restrict__ blocksum, unsigned int* __restrict__ blockbase) {
    __shared__ unsigned int wsum[16];
    int t = threadIdx.x, lane = t & 63, w = t >> 6;
    unsigned int own = blocksum[t];
    unsigned int v = own;
    #pragma unroll
    for (int off = 1; off < 64; off <<= 1) {
        unsigned int u = __shfl_up((int)v, off, 64);
        if (lane >= off) v += u;
    }
    if (lane == 63) wsum[w] = v;
    __syncthreads();
    unsigned int base = 0;
    for (int i = 0; i < w; ++i) base += wsum[i];
    blockbase[t] = v + base - own;   // exclusive
}

// ---- K2c: per-chunk exclusive scan + base -> global offsets ----
__global__ __launch_bounds__(256) void offsets_kernel(
    const unsigned int* __restrict__ counts, const unsigned int* __restrict__ blockbase,
    unsigned int* __restrict__ offsets, int n) {
    __shared__ unsigned int wsum[4];
    int t = threadIdx.x, b = blockIdx.x, lane = t & 63, w = t >> 6;
    unsigned int own = counts[b * 256 + t];
    unsigned int v = own;
    #pragma unroll
    for (int off = 1; off < 64; off <<= 1) {
        unsigned int u = __shfl_up((int)v, off, 64);
        if (lane >= off) v += u;
    }
    if (lane == 63) wsum[w] = v;
    __syncthreads();
    unsigned int base = blockbase[b];
    for (int i = 0; i < w; ++i) base += wsum[i];
    unsigned int incl = v + base;
    offsets[b * 256 + t] = incl - own;               // exclusive
    if (b == SCAN_BLOCKS - 1 && t == 255) offsets[NSEG] = incl;  // == n
}

// ---- K3: scatter point ids into cell-sorted order ----
__global__ __launch_bounds__(256) void reorder_kernel(
    const unsigned int* __restrict__ cellrank,
    const unsigned int* __restrict__ offsets, unsigned int* __restrict__ order, int n) {
    int stride = gridDim.x * blockDim.x;
    for (int p = blockIdx.x * blockDim.x + threadIdx.x; p < n; p += stride) {
        unsigned int u = __builtin_nontemporal_load(&cellrank[p]);
        unsigned int c = u >> RANK_BITS;
        order[offsets[c] + (u & RANK_MASK)] = (unsigned int)p;
    }
}

// ---- K4: one 16-lane group per cell, 4 cells per wave ----
// MEASUREMENT: whole cell loop repeated GATHER_REPS times (idempotent
// stores). Opaque-pointer asm per rep prevents hoisting/DCE of the
// repeated loads, so reps 2..R do real memory work (warm-L3).
__global__ __launch_bounds__(256) void gather_kernel(
    const float* __restrict__ x, const unsigned int* __restrict__ offsets,
    const unsigned int* __restrict__ order, float* __restrict__ out) {
    int t = threadIdx.x;
    int lane = t & 63;
    int sub = lane >> 4;       // which of the wave's 4 cells
    int cg  = lane & 15;       // channel quad: channels cg*4 .. cg*4+3
    int gw = (int)((blockIdx.x * blockDim.x + t) >> 6);
    int nw = (int)((gridDim.x * blockDim.x) >> 6);
    const float NEG_INF = -__builtin_inff();

    for (int rep = 0; rep < GATHER_REPS; ++rep) {
        // opaque copies: compiler cannot prove reps redundant
        const float* xp = x;
        const unsigned int* op = order;
        const unsigned int* ofp = offsets;
        asm volatile("" : "+v"(xp), "+v"(op), "+v"(ofp));

        for (int g = gw; g < NSEG / 4; g += nw) {
            int c = g * 4 + sub;
            unsigned int s = ofp[c];       // group-uniform
            unsigned int e = ofp[c + 1];
            unsigned int cnt = e - s;
            vf4 acc = (vf4)(NEG_INF);

            unsigned int k = 0;
            for (; k + 4 <= cnt; k += 4) { // 4 rows in flight per group
                unsigned int p0 = op[s + k];
                unsigned int p1 = op[s + k + 1];
                unsigned int p2 = op[s + k + 2];
                unsigned int p3 = op[s + k + 3];
                vf4 v0 = *(const vf4*)&xp[(size_t)p0 * NCH + (size_t)cg * 4];
                vf4 v1 = *(const vf4*)&xp[(size_t)p1 * NCH + (size_t)cg * 4];
                vf4 v2 = *(const vf4*)&xp[(size_t)p2 * NCH + (size_t)cg * 4];
                vf4 v3 = *(const vf4*)&xp[(size_t)p3 * NCH + (size_t)cg * 4];
                acc.x = fmaxf(fmaxf(fmaxf(acc.x, v0.x), fmaxf(v1.x, v2.x)), v3.x);
                acc.y = fmaxf(fmaxf(fmaxf(acc.y, v0.y), fmaxf(v1.y, v2.y)), v3.y);
                acc.z = fmaxf(fmaxf(fmaxf(acc.z, v0.z), fmaxf(v1.z, v2.z)), v3.z);
                acc.w = fmaxf(fmaxf(fmaxf(acc.w, v0.w), fmaxf(v1.w, v2.w)), v3.w);
            }
            for (; k < cnt; ++k) {         // tail, no duplicate loads
                unsigned int p = op[s + k];
                vf4 v = *(const vf4*)&xp[(size_t)p * NCH + (size_t)cg * 4];
                acc.x = fmaxf(acc.x, v.x);
                acc.y = fmaxf(acc.y, v.y);
                acc.z = fmaxf(acc.z, v.z);
                acc.w = fmaxf(acc.w, v.w);
            }
            if (cnt == 0u) acc = (vf4)(0.0f);  // empty cell -> 0
            __builtin_nontemporal_store(
                acc, (vf4*)&out[(size_t)c * NCH + (size_t)cg * 4]);
        }
    }
}

extern "C" void kernel_launch(void* const* d_in, const int* in_sizes, int n_in,
                              void* d_out, int out_size, void* d_ws, size_t ws_size,
                              hipStream_t stream) {
    const float* x   = (const float*)d_in[0];
    const int* pos   = (const int*)d_in[1];
    const int* batch = (const int*)d_in[2];
    float* out = (float*)d_out;
    int n = in_sizes[2];

    // workspace layout (~10 MB)
    unsigned int* counts    = (unsigned int*)d_ws;          // NSEG
    unsigned int* offsets   = counts + NSEG;                // NSEG + 1
    unsigned int* blocksum  = offsets + NSEG + 1;           // 1024
    unsigned int* blockbase = blocksum + 1024;              // 1024
    unsigned int* cellrank  = blockbase + 1024;             // N
    unsigned int* order     = cellrank + n;                 // N

    (void)hipMemsetAsync(counts, 0, (size_t)NSEG * sizeof(unsigned int), stream);

    count_kernel<<<4096, 256, 0, stream>>>(pos, batch, counts, cellrank, n);
    reduce_kernel<<<SCAN_BLOCKS, 256, 0, stream>>>(counts, blocksum);
    scanblock_kernel<<<1, 1024, 0, stream>>>(blocksum, blockbase);
    offsets_kernel<<<SCAN_BLOCKS, 256, 0, stream>>>(counts, blockbase, offsets, n);
    reorder_kernel<<<4096, 256, 0, stream>>>(cellrank, offsets, order, n);
    gather_kernel<<<2048, 256, 0, stream>>>(x, offsets, order, out);
}

// Round 7
// 408.885 us; speedup vs baseline: 1.2855x; 1.2855x over previous
//
#include <hip/hip_runtime.h>

#define POOL_SHIFT 2
#define GRID_DIM 64
#define NUM_CELLS 4096
#define NCH 64
#define BATCH 64
#define QCS 16                      // 16 channel-quads of 4 channels
#define SENTINEL ((int)0x80000000)  // maps to no real float (only NaN)

typedef float vf4 __attribute__((ext_vector_type(4)));

// ---- K0: batch row ranges (batch is sorted) ----
__global__ __launch_bounds__(256) void bounds_kernel(
    const int* __restrict__ batch, int* __restrict__ bstart, int n) {
    int p = blockIdx.x * blockDim.x + threadIdx.x;
    if (p >= n) return;
    int b = batch[p];
    if (p == 0) {
        for (int i = 0; i <= b; ++i) bstart[i] = 0;
    } else {
        int pb = batch[p - 1];
        for (int i = pb + 1; i <= b; ++i) bstart[i] = p;
    }
    if (p == n - 1) {
        for (int i = b + 1; i <= BATCH; ++i) bstart[i] = n;
    }
}

// order-preserving float->int map (finite floats; inputs have no NaN)
__device__ __forceinline__ int fmap(float f) {
    int i = __float_as_int(f);
    return i >= 0 ? i : (i ^ 0x7fffffff);
}
__device__ __forceinline__ float funmap(int m) {
    if (m == SENTINEL) return 0.0f;              // empty cell -> 0 (ref semantics)
    return __int_as_float(m >= 0 ? m : (m ^ 0x7fffffff));
}

__device__ __forceinline__ void accum(int* acc, int2 pp, vf4 v) {
    int c = ((pp.x >> POOL_SHIFT) << 6) | (pp.y >> POOL_SHIFT);
    // plane-major acc[j][c]: bank = c & 31 (4096 % 32 == 0) -> ~2-way, free
    atomicMax(&acc[0 * NUM_CELLS + c], fmap(v.x));
    atomicMax(&acc[1 * NUM_CELLS + c], fmap(v.y));
    atomicMax(&acc[2 * NUM_CELLS + c], fmap(v.z));
    atomicMax(&acc[3 * NUM_CELLS + c], fmap(v.w));
}

// ---- K1: one workgroup per (batch, channel-quad). Streams the batch's
// rows in ROW ORDER (sequential HBM — avoids the 2.9 TB/s random-read
// wall measured in round 6), max-accumulates into a 64 KB LDS slice,
// then flushes. No sort, no order/rank arrays, no global atomics.
// blockIdx mapping: L = grp*128 + qc*8 + xcd  =>  all 16 quads of a
// batch land on one XCD (round-robin %8 heuristic) and are co-resident,
// so the 16-B x chunks and shared pos reads dedupe in that XCD's L2.
__global__ __launch_bounds__(256, 2) void pool_kernel(
    const float* __restrict__ x, const int* __restrict__ pos,
    const int* __restrict__ bstart, float* __restrict__ out) {
    __shared__ int acc[4 * NUM_CELLS];   // 64 KB, plane-major [j][cell]
    const int L  = (int)blockIdx.x;
    const int b  = ((L >> 7) << 3) | (L & 7);
    const int qc = (L >> 3) & 15;
    const int t  = threadIdx.x;

    for (int i = t; i < 4 * NUM_CELLS; i += 256) acc[i] = SENTINEL;
    __syncthreads();

    const int r0 = bstart[b], r1 = bstart[b + 1];
    const vf4* xq  = (const vf4*)x;      // row r, quad qc -> xq[r*16 + qc]
    const int2* pq = (const int2*)pos;

    int r = r0 + t;
    // 4 independent row-loads in flight per lane (16 KB/wave outstanding)
    for (; r + 768 < r1; r += 1024) {
        int2 pp0 = pq[r];
        int2 pp1 = pq[r + 256];
        int2 pp2 = pq[r + 512];
        int2 pp3 = pq[r + 768];
        vf4 v0 = xq[(size_t)r * QCS + qc];
        vf4 v1 = xq[(size_t)(r + 256) * QCS + qc];
        vf4 v2 = xq[(size_t)(r + 512) * QCS + qc];
        vf4 v3 = xq[(size_t)(r + 768) * QCS + qc];
        accum(acc, pp0, v0);
        accum(acc, pp1, v1);
        accum(acc, pp2, v2);
        accum(acc, pp3, v3);
    }
    for (; r < r1; r += 256) {
        int2 pp = pq[r];
        vf4 v = xq[(size_t)r * QCS + qc];
        accum(acc, pp, v);
    }
    __syncthreads();

    // flush: channels qc*4 .. qc*4+3 of every cell of batch b
    const size_t obase = (size_t)b * NUM_CELLS * NCH + (size_t)qc * 4;
    for (int c = t; c < NUM_CELLS; c += 256) {
        vf4 o;
        o.x = funmap(acc[0 * NUM_CELLS + c]);
        o.y = funmap(acc[1 * NUM_CELLS + c]);
        o.z = funmap(acc[2 * NUM_CELLS + c]);
        o.w = funmap(acc[3 * NUM_CELLS + c]);
        *(vf4*)&out[obase + (size_t)c * NCH] = o;   // L2 merges quad-siblings
    }
}

extern "C" void kernel_launch(void* const* d_in, const int* in_sizes, int n_in,
                              void* d_out, int out_size, void* d_ws, size_t ws_size,
                              hipStream_t stream) {
    const float* x   = (const float*)d_in[0];
    const int* pos   = (const int*)d_in[1];
    const int* batch = (const int*)d_in[2];
    float* out = (float*)d_out;
    int n = in_sizes[2];

    int* bstart = (int*)d_ws;           // BATCH + 1 ints

    bounds_kernel<<<(n + 255) / 256, 256, 0, stream>>>(batch, bstart, n);
    pool_kernel<<<BATCH * QCS, 256, 0, stream>>>(x, pos, bstart, out);
}